// Round 12
// baseline (246.872 us; speedup 1.0000x reference)
//
#include <hip/hip_runtime.h>

typedef unsigned int uint;
typedef unsigned short ushort;
typedef __attribute__((ext_vector_type(8))) short short8;   // 8 bf16
typedef __attribute__((ext_vector_type(4))) float f32x4;

#define NSH   100
#define NPRIM 8
#define NAOC  280
#define NAOS  260
#define NATOM 20
#define KP    288
#define NKB   9
#define MT    64            // points per block
#define NTHR  512           // 8 waves
#define NCOLP 272
#define BCH   (32 * NCOLP)  // ushorts per chunk image (8704)
#define RSQRT3 0.57735026918962576f
#define LOG2E  1.4426950408889634f
#define EPS   276           // epilogue row stride (floats)

// LDS layout (epilogue bounce [0..17664) aliases sRad after main loop)
#define O_RAD   0        // 100*64*4 = 25600
#define O_AH    25600    // 2 bufs * 4096 = 8192
#define O_AL    33792    // 8192
#define O_ZETA  41984    // 3200
#define O_COEF  45184    // 3200
#define O_CEN   48384    // 320
#define O_CX    48704    // 256
#define O_CY    48960    // 256
#define O_CZ    49216    // 256
#define O_NORMF 49472    // 1152
#define O_META  50624    // 1152 -> 51776
#define POOLSZ  51776    // 2 blocks/CU (LDS), VGPR target <=128

__device__ __forceinline__ ushort bf16_rne(float x) {
    uint u = __float_as_uint(x);
    return (ushort)((u + 0x7FFFu + ((u >> 16) & 1u)) >> 16);
}
__device__ __forceinline__ float bf16_to_f(ushort h) {
    return __uint_as_float(((uint)h) << 16);
}
__device__ __forceinline__ uint cvt_pk_bf16(float a, float b) {
    uint r;
    asm("v_cvt_pk_bf16_f32 %0, %1, %2" : "=v"(r) : "v"(a), "v"(b));
    return r;
}

__device__ __forceinline__ int calc_meta(int k, float& anorm) {
    int shell = 0, atom = 0, s1 = 0, s2 = 0;
    anorm = 1.0f;
    if (k < 40) {
        atom = k >> 1; shell = 5 * atom + (k & 1);
    } else if (k < 160) {
        int i = k - 40; int ip = i / 3; int c = i - 3 * ip;
        atom = ip >> 1; shell = 5 * atom + 2 + (ip & 1); s1 = 1 + c;
    } else if (k < NAOC) {
        int i = k - 160; atom = i / 6; shell = 5 * atom + 4; int c = i - 6 * atom;
        if      (c == 0) { s1 = 1; s2 = 1; }
        else if (c == 1) { s1 = 1; s2 = 2; }
        else if (c == 2) { s1 = 1; s2 = 3; }
        else if (c == 3) { s1 = 2; s2 = 2; }
        else if (c == 4) { s1 = 2; s2 = 3; }
        else             { s1 = 3; s2 = 3; }
        if (c == 0 || c == 3 || c == 5) anorm = RSQRT3;
    }
    return shell | (atom << 7) | (s1 << 12) | (s2 << 14);
}

// ---- prep: split cart2sph to bf16 hi/lo frag image + meta/normf tables ----
__global__ void prep_b(const float* __restrict__ c2s, const float* __restrict__ norm,
                       ushort* __restrict__ wsHi, ushort* __restrict__ wsLo,
                       int* __restrict__ wsMeta, float* __restrict__ wsNorm) {
    if (blockIdx.x == 0) {
        for (int k = threadIdx.x; k < KP; k += 256) {
            float an;
            int m = calc_meta(k, an);
            wsMeta[k] = m;
            wsNorm[k] = (k < NAOC ? norm[k] : 0.0f) * an;
        }
    }
    int id = blockIdx.x * 256 + threadIdx.x;
    if (id >= KP * NCOLP) return;
    int k = id / NCOLP, col = id % NCOLP;
    float v = (k < NAOC && col < NAOS) ? c2s[k * NAOS + col] : 0.0f;
    ushort hi = bf16_rne(v);
    ushort lo = bf16_rne(v - bf16_to_f(hi));
    int off = (k >> 5) * BCH +
              (((col >> 4) * 4 + ((k & 31) >> 3)) * 16 + (col & 15)) * 8 + (k & 7);
    wsHi[off] = hi;
    wsLo[off] = lo;
}

template <bool USEWS>
__global__ __launch_bounds__(NTHR, 4) void gto_mfma(
    const float* __restrict__ coords, const float* __restrict__ centers,
    const float* __restrict__ zetas, const float* __restrict__ coeffs,
    const float* __restrict__ norm, const float* __restrict__ c2s,
    const ushort* __restrict__ wsHi, const ushort* __restrict__ wsLo,
    const int* __restrict__ wsMeta, const float* __restrict__ wsNorm,
    float* __restrict__ out, int n)
{
    __shared__ __align__(16) char smem[POOLSZ];
    float*  sRad  = (float*)(smem + O_RAD);
    float*  sZeta = (float*)(smem + O_ZETA);
    float*  sCoef = (float*)(smem + O_COEF);
    float4* sCen4 = (float4*)(smem + O_CEN);
    float*  sCx   = (float*)(smem + O_CX);
    float*  sCy   = (float*)(smem + O_CY);
    float*  sCz   = (float*)(smem + O_CZ);
    float*  sNormF= (float*)(smem + O_NORMF);
    int*    sMeta = (int*)(smem + O_META);

    const int t = threadIdx.x, lane = t & 63, w = t >> 6;
    const int lr = lane & 15, lg4 = lane >> 4;
    const int P0 = blockIdx.x * MT;

    // ---- stage constants ----
    for (int i = t; i < NSH * NPRIM; i += NTHR) {
        sZeta[i] = zetas[i] * LOG2E;
        sCoef[i] = coeffs[i];
    }
    if (t < NATOM)
        sCen4[t] = make_float4(centers[3 * t], centers[3 * t + 1], centers[3 * t + 2], 0.0f);
    if (t < MT * 3) {
        int gi = P0 * 3 + t;
        float v = (gi < 3 * n) ? coords[gi] : 0.0f;
        int p = t / 3, c = t - 3 * (t / 3);
        if (c == 0) sCx[p] = v; else if (c == 1) sCy[p] = v; else sCz[p] = v;
    }
    if (USEWS) {
        for (int i = t; i < KP; i += NTHR) { sMeta[i] = wsMeta[i]; sNormF[i] = wsNorm[i]; }
    } else {
        for (int k = t; k < KP; k += NTHR) {
            float an;
            sMeta[k] = calc_meta(k, an);
            sNormF[k] = (k < NAOC ? norm[k] : 0.0f) * an;
        }
    }
    __syncthreads();

    // ---- radial table rad[shell][point] ----
    #pragma unroll 1
    for (int it = 0; it < (NSH * MT + NTHR - 1) / NTHR; ++it) {
        int id = it * NTHR + t;
        if (id < NSH * MT) {
            int s = id >> 6, p = id & 63;
            int a = s / 5;
            float4 ca = sCen4[a];
            float dx = sCx[p] - ca.x;
            float dy = sCy[p] - ca.y;
            float dz = sCz[p] - ca.z;
            float r2 = dx * dx + dy * dy + dz * dz;
            float4 z0 = *(const float4*)&sZeta[s * NPRIM];
            float4 z1 = *(const float4*)&sZeta[s * NPRIM + 4];
            float4 c0 = *(const float4*)&sCoef[s * NPRIM];
            float4 c1 = *(const float4*)&sCoef[s * NPRIM + 4];
            float rad = c0.x * __builtin_amdgcn_exp2f(-z0.x * r2);
            rad += c0.y * __builtin_amdgcn_exp2f(-z0.y * r2);
            rad += c0.z * __builtin_amdgcn_exp2f(-z0.z * r2);
            rad += c0.w * __builtin_amdgcn_exp2f(-z0.w * r2);
            rad += c1.x * __builtin_amdgcn_exp2f(-z1.x * r2);
            rad += c1.y * __builtin_amdgcn_exp2f(-z1.y * r2);
            rad += c1.z * __builtin_amdgcn_exp2f(-z1.z * r2);
            rad += c1.w * __builtin_amdgcn_exp2f(-z1.w * r2);
            sRad[s * MT + p] = rad;
        }
    }

    // ---- A-build: thread (q = t>>6 in 0..7, pA = t&63) -> 4 consecutive k's ----
    // A buf layout (4096B per buffer): [oct:4][p:64][8k x 2B]
    const int pA = t & 63, q = t >> 6;
    auto buildA = [&](int kb2) {
        const float cxp = sCx[pA], cyp = sCy[pA], czp = sCz[pA];
        const int k0 = kb2 * 32 + q * 4;
        int4   m4  = *(const int4*)&sMeta[k0];
        float4 nf4 = *(const float4*)&sNormF[k0];
        const int   mk[4] = {m4.x, m4.y, m4.z, m4.w};
        const float nf[4] = {nf4.x, nf4.y, nf4.z, nf4.w};
        float v[4];
        #pragma unroll
        for (int j = 0; j < 4; ++j) {
            int meta = mk[j];
            int s = meta & 127, a = (meta >> 7) & 31;
            int s1 = (meta >> 12) & 3, s2 = (meta >> 14) & 3;
            float4 ca = sCen4[a];
            float dx = cxp - ca.x, dy = cyp - ca.y, dz = czp - ca.z;
            float m1 = (s1 == 0) ? 1.0f : ((s1 == 1) ? dx : ((s1 == 2) ? dy : dz));
            float m2v = (s2 == 0) ? 1.0f : ((s2 == 1) ? dx : ((s2 == 2) ? dy : dz));
            v[j] = sRad[s * MT + pA] * (m1 * m2v) * nf[j];
        }
        uint h01 = cvt_pk_bf16(v[0], v[1]);
        uint h23 = cvt_pk_bf16(v[2], v[3]);
        float r0 = v[0] - __uint_as_float(h01 << 16);
        float r1 = v[1] - __uint_as_float(h01 & 0xffff0000u);
        float r2 = v[2] - __uint_as_float(h23 << 16);
        float r3 = v[3] - __uint_as_float(h23 & 0xffff0000u);
        uint l01 = cvt_pk_bf16(r0, r1);
        uint l23 = cvt_pk_bf16(r2, r3);
        const int boff = (kb2 & 1) * 4096 + (q >> 1) * 1024 + pA * 16 + (q & 1) * 8;
        *(uint2*)(smem + O_AH + boff) = make_uint2(h01, h23);
        *(uint2*)(smem + O_AL + boff) = make_uint2(l01, l23);
    };

    __syncthreads();   // sRad ready
    buildA(0);

    // ---- B running pointers: wave w owns tiles {2w, 2w+1} (+16 for w0) ----
    const ushort* pH  = wsHi + (2 * w * 64 + lane) * 8;
    const ushort* pL  = wsLo + (2 * w * 64 + lane) * 8;
    const ushort* pH2 = wsHi + (16 * 64 + lane) * 8;
    const ushort* pL2 = wsLo + (16 * 64 + lane) * 8;

    f32x4 acc[3][4];
    #pragma unroll
    for (int ti = 0; ti < 3; ++ti)
        #pragma unroll
        for (int m = 0; m < 4; ++m)
            acc[ti][m] = (f32x4){0.0f, 0.0f, 0.0f, 0.0f};

    #pragma unroll 1
    for (int kb = 0; kb < NKB; ++kb) {
        __syncthreads();   // A(kb) ds_writes visible

        const int base = (kb & 1) * 4096;
        short8 aH[4], aL[4];
        #pragma unroll
        for (int m = 0; m < 4; ++m) {
            const int off = base + lg4 * 1024 + (m * 16 + lr) * 16;
            aH[m] = *(const short8*)(smem + O_AH + off);
            aL[m] = *(const short8*)(smem + O_AL + off);
        }

        if (kb + 1 < NKB) buildA(kb + 1);

        #pragma unroll
        for (int ti = 0; ti < 3; ++ti) {
            if (ti < 2 || w == 0) {
                short8 bh, bl;
                if (USEWS) {
                    if (ti == 0)      { bh = *(const short8*)pH;          bl = *(const short8*)pL; }
                    else if (ti == 1) { bh = *(const short8*)(pH + 512);  bl = *(const short8*)(pL + 512); }
                    else              { bh = *(const short8*)pH2;         bl = *(const short8*)pL2; }
                } else {
                    int nt = (ti == 2) ? 16 : (2 * w + ti);
                    #pragma unroll
                    for (int j = 0; j < 8; ++j) {
                        int k = kb * 32 + lg4 * 8 + j;
                        int col = nt * 16 + lr;
                        float v = (k < NAOC && col < NAOS) ? c2s[k * NAOS + col] : 0.0f;
                        ushort hi = bf16_rne(v);
                        bh[j] = (short)hi;
                        bl[j] = (short)bf16_rne(v - bf16_to_f(hi));
                    }
                }
                #pragma unroll
                for (int m = 0; m < 4; ++m)
                    acc[ti][m] = __builtin_amdgcn_mfma_f32_16x16x32_bf16(aH[m], bh, acc[ti][m], 0, 0, 0);
                #pragma unroll
                for (int m = 0; m < 4; ++m)
                    acc[ti][m] = __builtin_amdgcn_mfma_f32_16x16x32_bf16(aH[m], bl, acc[ti][m], 0, 0, 0);
                #pragma unroll
                for (int m = 0; m < 4; ++m)
                    acc[ti][m] = __builtin_amdgcn_mfma_f32_16x16x32_bf16(aL[m], bh, acc[ti][m], 0, 0, 0);
            }
        }
        pH += BCH; pL += BCH; pH2 += BCH; pL2 += BCH;
    }

    // ---- epilogue: four 16-row quarters through a 17.7KB bounce ----
    float* ep = (float*)smem;
    #pragma unroll 1
    for (int qm = 0; qm < 4; ++qm) {
        __syncthreads();   // previous contents consumed
        #pragma unroll
        for (int ti = 0; ti < 3; ++ti) {
            if (ti < 2 || w == 0) {
                int nt = (ti == 2) ? 16 : (2 * w + ti);
                int col = nt * 16 + lr;
                #pragma unroll
                for (int r = 0; r < 4; ++r)
                    ep[(lg4 * 4 + r) * EPS + col] = acc[ti][qm][r];
            }
        }
        __syncthreads();
        const int row = t >> 5;          // 0..15
        const int c   = t & 31;
        const int P   = P0 + qm * 16 + row;
        if (P < n) {
            #pragma unroll
            for (int c4 = 0; c4 < 3; ++c4) {
                int col4 = c + c4 * 32;
                if (col4 < 65)
                    *(float4*)&out[(size_t)P * NAOS + col4 * 4] =
                        *(const float4*)&ep[row * EPS + col4 * 4];
            }
        }
    }
}

extern "C" void kernel_launch(void* const* d_in, const int* in_sizes, int n_in,
                              void* d_out, int out_size, void* d_ws, size_t ws_size,
                              hipStream_t stream) {
    const float* coords  = (const float*)d_in[0];
    const float* centers = (const float*)d_in[1];
    const float* zetas   = (const float*)d_in[2];
    const float* coeffs  = (const float*)d_in[3];
    const float* norm    = (const float*)d_in[4];
    const float* c2s     = (const float*)d_in[5];
    float* out = (float*)d_out;
    int n = in_sizes[0] / 3;
    int grid = (n + MT - 1) / MT;

    ushort* wsHi = (ushort*)d_ws;
    ushort* wsLo = wsHi + (size_t)KP * NCOLP;
    int*    wsMeta = (int*)(wsLo + (size_t)KP * NCOLP);
    float*  wsNorm = (float*)(wsMeta + KP);
    const size_t WS_NEED = (size_t)2 * KP * NCOLP * sizeof(ushort) + KP * 8;

    if (ws_size >= WS_NEED) {
        prep_b<<<(KP * NCOLP + 255) / 256, 256, 0, stream>>>(c2s, norm, wsHi, wsLo, wsMeta, wsNorm);
        gto_mfma<true><<<grid, NTHR, 0, stream>>>(coords, centers, zetas, coeffs, norm, c2s,
                                                  wsHi, wsLo, wsMeta, wsNorm, out, n);
    } else {
        gto_mfma<false><<<grid, NTHR, 0, stream>>>(coords, centers, zetas, coeffs, norm, c2s,
                                                   nullptr, nullptr, nullptr, nullptr, out, n);
    }
}

// Round 13
// 103.563 us; speedup vs baseline: 2.3838x; 2.3838x over previous
//
#include <hip/hip_runtime.h>

typedef unsigned int uint;
typedef unsigned short ushort;
typedef __attribute__((ext_vector_type(8))) short short8;   // 8 bf16
typedef __attribute__((ext_vector_type(4))) float f32x4;

#define NSH   100
#define NPRIM 8
#define NAOC  280
#define NAOS  260
#define NATOM 20
#define KP    288
#define NKB   9
#define MT    64            // points per block
#define NTHR  512           // 8 waves
#define NCOLP 272
#define BCH   (32 * NCOLP)  // ushorts per chunk image (8704)
#define RSQRT3 0.57735026918962576f
#define LOG2E  1.4426950408889634f
#define EPS   276           // epilogue row stride (floats)

// LDS layout (epilogue bounce [0..17664) aliases sRad after main loop)
#define O_RAD   0        // 100*64*4 = 25600
#define O_AH    25600    // 2 bufs * 4096 = 8192
#define O_AL    33792    // 8192
#define O_ZETA  41984    // 3200
#define O_COEF  45184    // 3200
#define O_CEN   48384    // 320
#define O_CX    48704    // 256
#define O_CY    48960    // 256
#define O_CZ    49216    // 256
#define O_NORMF 49472    // 1152
#define O_META  50624    // 1152 -> 51776
#define POOLSZ  51776    // 2 blocks/CU (LDS), VGPR target <=128

__device__ __forceinline__ ushort bf16_rne(float x) {
    uint u = __float_as_uint(x);
    return (ushort)((u + 0x7FFFu + ((u >> 16) & 1u)) >> 16);
}
__device__ __forceinline__ float bf16_to_f(ushort h) {
    return __uint_as_float(((uint)h) << 16);
}
__device__ __forceinline__ uint cvt_pk_bf16(float a, float b) {
    uint r;
    asm("v_cvt_pk_bf16_f32 %0, %1, %2" : "=v"(r) : "v"(a), "v"(b));
    return r;
}

__device__ __forceinline__ int calc_meta(int k, float& anorm) {
    int shell = 0, atom = 0, s1 = 0, s2 = 0;
    anorm = 1.0f;
    if (k < 40) {
        atom = k >> 1; shell = 5 * atom + (k & 1);
    } else if (k < 160) {
        int i = k - 40; int ip = i / 3; int c = i - 3 * ip;
        atom = ip >> 1; shell = 5 * atom + 2 + (ip & 1); s1 = 1 + c;
    } else if (k < NAOC) {
        int i = k - 160; atom = i / 6; shell = 5 * atom + 4; int c = i - 6 * atom;
        if      (c == 0) { s1 = 1; s2 = 1; }
        else if (c == 1) { s1 = 1; s2 = 2; }
        else if (c == 2) { s1 = 1; s2 = 3; }
        else if (c == 3) { s1 = 2; s2 = 2; }
        else if (c == 4) { s1 = 2; s2 = 3; }
        else             { s1 = 3; s2 = 3; }
        if (c == 0 || c == 3 || c == 5) anorm = RSQRT3;
    }
    return shell | (atom << 7) | (s1 << 12) | (s2 << 14);
}

// ---- prep: split cart2sph to bf16 hi/lo frag image + meta/normf tables ----
__global__ void prep_b(const float* __restrict__ c2s, const float* __restrict__ norm,
                       ushort* __restrict__ wsHi, ushort* __restrict__ wsLo,
                       int* __restrict__ wsMeta, float* __restrict__ wsNorm) {
    if (blockIdx.x == 0) {
        for (int k = threadIdx.x; k < KP; k += 256) {
            float an;
            int m = calc_meta(k, an);
            wsMeta[k] = m;
            wsNorm[k] = (k < NAOC ? norm[k] : 0.0f) * an;
        }
    }
    int id = blockIdx.x * 256 + threadIdx.x;
    if (id >= KP * NCOLP) return;
    int k = id / NCOLP, col = id % NCOLP;
    float v = (k < NAOC && col < NAOS) ? c2s[k * NAOS + col] : 0.0f;
    ushort hi = bf16_rne(v);
    ushort lo = bf16_rne(v - bf16_to_f(hi));
    int off = (k >> 5) * BCH +
              (((col >> 4) * 4 + ((k & 31) >> 3)) * 16 + (col & 15)) * 8 + (k & 7);
    wsHi[off] = hi;
    wsLo[off] = lo;
}

template <bool USEWS>
__global__ __launch_bounds__(NTHR, 4) void gto_mfma(
    const float* __restrict__ coords, const float* __restrict__ centers,
    const float* __restrict__ zetas, const float* __restrict__ coeffs,
    const float* __restrict__ norm, const float* __restrict__ c2s,
    const ushort* __restrict__ wsHi, const ushort* __restrict__ wsLo,
    const int* __restrict__ wsMeta, const float* __restrict__ wsNorm,
    float* __restrict__ out, int n)
{
    __shared__ __align__(16) char smem[POOLSZ];
    float*  sRad  = (float*)(smem + O_RAD);
    float*  sZeta = (float*)(smem + O_ZETA);
    float*  sCoef = (float*)(smem + O_COEF);
    float4* sCen4 = (float4*)(smem + O_CEN);
    float*  sCx   = (float*)(smem + O_CX);
    float*  sCy   = (float*)(smem + O_CY);
    float*  sCz   = (float*)(smem + O_CZ);
    float*  sNormF= (float*)(smem + O_NORMF);
    int*    sMeta = (int*)(smem + O_META);

    const int t = threadIdx.x, lane = t & 63, w = t >> 6;
    const int lr = lane & 15, lg4 = lane >> 4;
    const int P0 = blockIdx.x * MT;

    // ---- stage constants ----
    for (int i = t; i < NSH * NPRIM; i += NTHR) {
        sZeta[i] = zetas[i] * LOG2E;
        sCoef[i] = coeffs[i];
    }
    if (t < NATOM)
        sCen4[t] = make_float4(centers[3 * t], centers[3 * t + 1], centers[3 * t + 2], 0.0f);
    if (t < MT * 3) {
        int gi = P0 * 3 + t;
        float v = (gi < 3 * n) ? coords[gi] : 0.0f;
        int p = t / 3, c = t - 3 * (t / 3);
        if (c == 0) sCx[p] = v; else if (c == 1) sCy[p] = v; else sCz[p] = v;
    }
    if (USEWS) {
        for (int i = t; i < KP; i += NTHR) { sMeta[i] = wsMeta[i]; sNormF[i] = wsNorm[i]; }
    } else {
        for (int k = t; k < KP; k += NTHR) {
            float an;
            sMeta[k] = calc_meta(k, an);
            sNormF[k] = (k < NAOC ? norm[k] : 0.0f) * an;
        }
    }
    __syncthreads();

    // ---- radial table rad[shell][point] ----
    #pragma unroll 1
    for (int it = 0; it < (NSH * MT + NTHR - 1) / NTHR; ++it) {
        int id = it * NTHR + t;
        if (id < NSH * MT) {
            int s = id >> 6, p = id & 63;
            int a = s / 5;
            float4 ca = sCen4[a];
            float dx = sCx[p] - ca.x;
            float dy = sCy[p] - ca.y;
            float dz = sCz[p] - ca.z;
            float r2 = dx * dx + dy * dy + dz * dz;
            float4 z0 = *(const float4*)&sZeta[s * NPRIM];
            float4 z1 = *(const float4*)&sZeta[s * NPRIM + 4];
            float4 c0 = *(const float4*)&sCoef[s * NPRIM];
            float4 c1 = *(const float4*)&sCoef[s * NPRIM + 4];
            float rad = c0.x * __builtin_amdgcn_exp2f(-z0.x * r2);
            rad += c0.y * __builtin_amdgcn_exp2f(-z0.y * r2);
            rad += c0.z * __builtin_amdgcn_exp2f(-z0.z * r2);
            rad += c0.w * __builtin_amdgcn_exp2f(-z0.w * r2);
            rad += c1.x * __builtin_amdgcn_exp2f(-z1.x * r2);
            rad += c1.y * __builtin_amdgcn_exp2f(-z1.y * r2);
            rad += c1.z * __builtin_amdgcn_exp2f(-z1.z * r2);
            rad += c1.w * __builtin_amdgcn_exp2f(-z1.w * r2);
            sRad[s * MT + p] = rad;
        }
    }

    // ---- A-build: thread (q = t>>6 in 0..7, pA = t&63) -> 4 consecutive k's ----
    // A buf layout (4096B per buffer): [qpair:4][p:64][16B cell]
    const int pA = t & 63, q = t >> 6;
    auto buildA = [&](int kb2) {
        const float cxp = sCx[pA], cyp = sCy[pA], czp = sCz[pA];
        const int k0 = kb2 * 32 + q * 4;
        int4   m4  = *(const int4*)&sMeta[k0];
        float4 nf4 = *(const float4*)&sNormF[k0];
        const int   mk[4] = {m4.x, m4.y, m4.z, m4.w};
        const float nf[4] = {nf4.x, nf4.y, nf4.z, nf4.w};
        float v[4];
        #pragma unroll
        for (int j = 0; j < 4; ++j) {
            int meta = mk[j];
            int s = meta & 127, a = (meta >> 7) & 31;
            int s1 = (meta >> 12) & 3, s2 = (meta >> 14) & 3;
            float4 ca = sCen4[a];
            float dx = cxp - ca.x, dy = cyp - ca.y, dz = czp - ca.z;
            float m1 = (s1 == 0) ? 1.0f : ((s1 == 1) ? dx : ((s1 == 2) ? dy : dz));
            float m2v = (s2 == 0) ? 1.0f : ((s2 == 1) ? dx : ((s2 == 2) ? dy : dz));
            v[j] = sRad[s * MT + pA] * (m1 * m2v) * nf[j];
        }
        uint h01 = cvt_pk_bf16(v[0], v[1]);
        uint h23 = cvt_pk_bf16(v[2], v[3]);
        float r0 = v[0] - __uint_as_float(h01 << 16);
        float r1 = v[1] - __uint_as_float(h01 & 0xffff0000u);
        float r2 = v[2] - __uint_as_float(h23 << 16);
        float r3 = v[3] - __uint_as_float(h23 & 0xffff0000u);
        uint l01 = cvt_pk_bf16(r0, r1);
        uint l23 = cvt_pk_bf16(r2, r3);
        const int boff = (kb2 & 1) * 4096 + (q >> 1) * 1024 + pA * 16 + (q & 1) * 8;
        *(uint2*)(smem + O_AH + boff) = make_uint2(h01, h23);
        *(uint2*)(smem + O_AL + boff) = make_uint2(l01, l23);
    };

    __syncthreads();   // sRad ready
    buildA(0);

    // ---- B running pointers: wave w owns tiles {2w, 2w+1} (+16 for w0) ----
    const ushort* pH  = wsHi + (2 * w * 64 + lane) * 8;
    const ushort* pL  = wsLo + (2 * w * 64 + lane) * 8;
    const ushort* pH2 = wsHi + (16 * 64 + lane) * 8;
    const ushort* pL2 = wsLo + (16 * 64 + lane) * 8;

    f32x4 acc[3][4];
    #pragma unroll
    for (int ti = 0; ti < 3; ++ti)
        #pragma unroll
        for (int m = 0; m < 4; ++m)
            acc[ti][m] = (f32x4){0.0f, 0.0f, 0.0f, 0.0f};

    #pragma unroll 1
    for (int kb = 0; kb < NKB; ++kb) {
        __syncthreads();   // A(kb) ds_writes visible

        const int base = (kb & 1) * 4096;
        short8 aH[4], aL[4];
        #pragma unroll
        for (int m = 0; m < 4; ++m) {
            const int off = base + lg4 * 1024 + (m * 16 + lr) * 16;
            aH[m] = *(const short8*)(smem + O_AH + off);
            aL[m] = *(const short8*)(smem + O_AL + off);
        }

        if (kb + 1 < NKB) buildA(kb + 1);

        #pragma unroll
        for (int ti = 0; ti < 3; ++ti) {
            if (ti < 2 || w == 0) {
                short8 bh, bl;
                if (USEWS) {
                    if (ti == 0)      { bh = *(const short8*)pH;          bl = *(const short8*)pL; }
                    else if (ti == 1) { bh = *(const short8*)(pH + 512);  bl = *(const short8*)(pL + 512); }
                    else              { bh = *(const short8*)pH2;         bl = *(const short8*)pL2; }
                } else {
                    int nt = (ti == 2) ? 16 : (2 * w + ti);
                    #pragma unroll
                    for (int j = 0; j < 8; ++j) {
                        int k = kb * 32 + lg4 * 8 + j;
                        int col = nt * 16 + lr;
                        float v = (k < NAOC && col < NAOS) ? c2s[k * NAOS + col] : 0.0f;
                        ushort hi = bf16_rne(v);
                        bh[j] = (short)hi;
                        bl[j] = (short)bf16_rne(v - bf16_to_f(hi));
                    }
                }
                #pragma unroll
                for (int m = 0; m < 4; ++m)
                    acc[ti][m] = __builtin_amdgcn_mfma_f32_16x16x32_bf16(aH[m], bh, acc[ti][m], 0, 0, 0);
                #pragma unroll
                for (int m = 0; m < 4; ++m)
                    acc[ti][m] = __builtin_amdgcn_mfma_f32_16x16x32_bf16(aH[m], bl, acc[ti][m], 0, 0, 0);
                #pragma unroll
                for (int m = 0; m < 4; ++m)
                    acc[ti][m] = __builtin_amdgcn_mfma_f32_16x16x32_bf16(aL[m], bh, acc[ti][m], 0, 0, 0);
            }
        }
        pH += BCH; pL += BCH; pH2 += BCH; pL2 += BCH;
    }

    // ---- epilogue: four 16-row quarters; qm FULLY UNROLLED (R12 bug: runtime
    //      qm indexed acc[][] -> whole accumulator spilled to scratch, 1.4GB) ----
    float* ep = (float*)smem;
    #pragma unroll
    for (int qm = 0; qm < 4; ++qm) {
        __syncthreads();   // previous contents consumed
        #pragma unroll
        for (int ti = 0; ti < 3; ++ti) {
            if (ti < 2 || w == 0) {
                int nt = (ti == 2) ? 16 : (2 * w + ti);
                int col = nt * 16 + lr;
                #pragma unroll
                for (int r = 0; r < 4; ++r)
                    ep[(lg4 * 4 + r) * EPS + col] = acc[ti][qm][r];
            }
        }
        __syncthreads();
        const int row = t >> 5;          // 0..15
        const int c   = t & 31;
        const int P   = P0 + qm * 16 + row;
        if (P < n) {
            #pragma unroll
            for (int c4 = 0; c4 < 3; ++c4) {
                int col4 = c + c4 * 32;
                if (col4 < 65)
                    *(float4*)&out[(size_t)P * NAOS + col4 * 4] =
                        *(const float4*)&ep[row * EPS + col4 * 4];
            }
        }
    }
}

extern "C" void kernel_launch(void* const* d_in, const int* in_sizes, int n_in,
                              void* d_out, int out_size, void* d_ws, size_t ws_size,
                              hipStream_t stream) {
    const float* coords  = (const float*)d_in[0];
    const float* centers = (const float*)d_in[1];
    const float* zetas   = (const float*)d_in[2];
    const float* coeffs  = (const float*)d_in[3];
    const float* norm    = (const float*)d_in[4];
    const float* c2s     = (const float*)d_in[5];
    float* out = (float*)d_out;
    int n = in_sizes[0] / 3;
    int grid = (n + MT - 1) / MT;

    ushort* wsHi = (ushort*)d_ws;
    ushort* wsLo = wsHi + (size_t)KP * NCOLP;
    int*    wsMeta = (int*)(wsLo + (size_t)KP * NCOLP);
    float*  wsNorm = (float*)(wsMeta + KP);
    const size_t WS_NEED = (size_t)2 * KP * NCOLP * sizeof(ushort) + KP * 8;

    if (ws_size >= WS_NEED) {
        prep_b<<<(KP * NCOLP + 255) / 256, 256, 0, stream>>>(c2s, norm, wsHi, wsLo, wsMeta, wsNorm);
        gto_mfma<true><<<grid, NTHR, 0, stream>>>(coords, centers, zetas, coeffs, norm, c2s,
                                                  wsHi, wsLo, wsMeta, wsNorm, out, n);
    } else {
        gto_mfma<false><<<grid, NTHR, 0, stream>>>(coords, centers, zetas, coeffs, norm, c2s,
                                                   nullptr, nullptr, nullptr, nullptr, out, n);
    }
}

// Round 14
// 91.883 us; speedup vs baseline: 2.6868x; 1.1271x over previous
//
#include <hip/hip_runtime.h>

typedef unsigned int uint;
typedef unsigned short ushort;
typedef __attribute__((ext_vector_type(8))) short short8;   // 8 bf16
typedef __attribute__((ext_vector_type(4))) float f32x4;

#define NSH   100
#define NPRIM 8
#define NAOC  280
#define NAOS  260
#define NATOM 20
#define KP    288           // 20*14 + 8 pad
#define NKB   9
#define MT    32            // points per block
#define NTHR  256
#define NCOLP 272
#define BCH   (32 * NCOLP)  // ushorts per chunk image (8704)
#define RSQRT3 0.57735026918962576f
#define LOG2E  1.4426950408889634f
#define EPS   276           // epilogue row stride (floats)

// LDS layout. A image [36 cells][32 p][16B] built ONCE; epilogue bounce
// [0..17664) aliases the (then-dead) A-hi image.
#define O_AH    0        // 36*512 = 18432
#define O_AL    18432    // 18432 -> 36864
#define O_ZETA  36864    // 3200
#define O_COEF  40064    // 3200
#define O_CEN   43264    // 20*16 = 320
#define O_CX    43584    // 128
#define O_CY    43712    // 128
#define O_CZ    43840    // 128 -> 43968
#define POOLSZ  43968    // 3 blocks/CU

__device__ __forceinline__ ushort bf16_rne(float x) {
    uint u = __float_as_uint(x);
    return (ushort)((u + 0x7FFFu + ((u >> 16) & 1u)) >> 16);
}
__device__ __forceinline__ float bf16_to_f(ushort h) {
    return __uint_as_float(((uint)h) << 16);
}
__device__ __forceinline__ uint cvt_pk_bf16(float a, float b) {
    uint r;
    asm("v_cvt_pk_bf16_f32 %0, %1, %2" : "=v"(r) : "v"(a), "v"(b));
    return r;
}

// B source value in the NEW atom-major k ordering: k' = 14*a + i,
// i: 0,1 = s shells; 2..4 = p-shell0 xyz; 5..7 = p-shell1 xyz; 8..13 = d (xx,xy,xz,yy,yz,zz).
// normalization and the d anorm (1/sqrt(3) on xx,yy,zz) are folded in here.
__device__ __forceinline__ float b_src(const float* __restrict__ c2s,
                                       const float* __restrict__ norm,
                                       int kp, int col) {
    if (kp >= NAOC || col >= NAOS) return 0.0f;
    int a = kp / 14, i = kp - 14 * a;
    int ksrc; float an = 1.0f;
    if (i < 2)      ksrc = 2 * a + i;
    else if (i < 8) ksrc = 40 + 6 * a + (i - 2);
    else {
        ksrc = 160 + 6 * a + (i - 8);
        if (i == 8 || i == 11 || i == 13) an = RSQRT3;
    }
    return c2s[ksrc * NAOS + col] * norm[ksrc] * an;
}

// ---- prep: permuted+scaled cart2sph -> bf16 hi/lo MFMA frag image ----
__global__ void prep_b(const float* __restrict__ c2s, const float* __restrict__ norm,
                       ushort* __restrict__ wsHi, ushort* __restrict__ wsLo) {
    int id = blockIdx.x * 256 + threadIdx.x;
    if (id >= KP * NCOLP) return;
    int k = id / NCOLP, col = id % NCOLP;
    float v = b_src(c2s, norm, k, col);
    ushort hi = bf16_rne(v);
    ushort lo = bf16_rne(v - bf16_to_f(hi));
    int off = (k >> 5) * BCH +
              (((col >> 4) * 4 + ((k & 31) >> 3)) * 16 + (col & 15)) * 8 + (k & 7);
    wsHi[off] = hi;
    wsLo[off] = lo;
}

template <bool USEWS>
__global__ __launch_bounds__(NTHR, 4) void gto_mfma(
    const float* __restrict__ coords, const float* __restrict__ centers,
    const float* __restrict__ zetas, const float* __restrict__ coeffs,
    const float* __restrict__ norm, const float* __restrict__ c2s,
    const ushort* __restrict__ wsHi, const ushort* __restrict__ wsLo,
    float* __restrict__ out, int n)
{
    __shared__ __align__(16) char smem[POOLSZ];
    float*  sZeta = (float*)(smem + O_ZETA);
    float*  sCoef = (float*)(smem + O_COEF);
    float4* sCen4 = (float4*)(smem + O_CEN);
    float*  sCx   = (float*)(smem + O_CX);
    float*  sCy   = (float*)(smem + O_CY);
    float*  sCz   = (float*)(smem + O_CZ);

    const int t = threadIdx.x, lane = t & 63, w = t >> 6;
    const int lr = lane & 15, lg4 = lane >> 4;
    const int P0 = blockIdx.x * MT;

    // ---- stage constants ----
    for (int i = t; i < NSH * NPRIM; i += NTHR) {
        sZeta[i] = zetas[i] * LOG2E;           // pre-fold log2e for v_exp_f32
        sCoef[i] = coeffs[i];
    }
    if (t < NATOM)
        sCen4[t] = make_float4(centers[3 * t], centers[3 * t + 1], centers[3 * t + 2], 0.0f);
    if (t < MT * 3) {
        int gi = P0 * 3 + t;
        float v = (gi < 3 * n) ? coords[gi] : 0.0f;
        int p = t / 3, c = t - 3 * (t / 3);
        if (c == 0) sCx[p] = v; else if (c == 1) sCy[p] = v; else sCz[p] = v;
    }
    // zero the K-pad cell (k' 280..287 = cell 35) in both images
    if (t < 64)        *(uint2*)(smem + O_AH + 35 * 512 + t * 8) = make_uint2(0u, 0u);
    else if (t < 128)  *(uint2*)(smem + O_AL + 35 * 512 + (t - 64) * 8) = make_uint2(0u, 0u);
    __syncthreads();

    // ---- A-build: FULLY STATIC per (point, atom); entire 280-k image once ----
    // thread: pA = t&31 (point), ag = t>>5 (atom group): ag<4 -> 3 atoms, else 2.
    const int pA = t & 31, ag = t >> 5;
    const float cxp = sCx[pA], cyp = sCy[pA], czp = sCz[pA];

    auto doAtom = [&](int a) {
        float4 ca = sCen4[a];
        float dx = cxp - ca.x, dy = cyp - ca.y, dz = czp - ca.z;
        float r2 = dx * dx + dy * dy + dz * dz;
        float rad[5];
        #pragma unroll
        for (int sh = 0; sh < 5; ++sh) {
            const float* z = &sZeta[(5 * a + sh) * NPRIM];
            const float* cf = &sCoef[(5 * a + sh) * NPRIM];
            float4 z0 = *(const float4*)z,  z1 = *(const float4*)(z + 4);
            float4 c0 = *(const float4*)cf, c1 = *(const float4*)(cf + 4);
            float r = c0.x * __builtin_amdgcn_exp2f(-z0.x * r2);
            r += c0.y * __builtin_amdgcn_exp2f(-z0.y * r2);
            r += c0.z * __builtin_amdgcn_exp2f(-z0.z * r2);
            r += c0.w * __builtin_amdgcn_exp2f(-z0.w * r2);
            r += c1.x * __builtin_amdgcn_exp2f(-z1.x * r2);
            r += c1.y * __builtin_amdgcn_exp2f(-z1.y * r2);
            r += c1.z * __builtin_amdgcn_exp2f(-z1.z * r2);
            r += c1.w * __builtin_amdgcn_exp2f(-z1.w * r2);
            rad[sh] = r;
        }
        float xx = dx * dx, xy = dx * dy, xz = dx * dz;
        float yy = dy * dy, yz = dy * dz, zz = dz * dz;
        float v[14] = { rad[0], rad[1],
                        dx * rad[2], dy * rad[2], dz * rad[2],
                        dx * rad[3], dy * rad[3], dz * rad[3],
                        xx * rad[4], xy * rad[4], xz * rad[4],
                        yy * rad[4], yz * rad[4], zz * rad[4] };
        const int k0 = a * 14;   // always even -> pairs are 4B aligned in cells
        #pragma unroll
        for (int pr = 0; pr < 7; ++pr) {
            int k = k0 + 2 * pr;
            uint h = cvt_pk_bf16(v[2 * pr], v[2 * pr + 1]);
            float r0 = v[2 * pr]     - __uint_as_float(h << 16);
            float r1 = v[2 * pr + 1] - __uint_as_float(h & 0xffff0000u);
            uint l = cvt_pk_bf16(r0, r1);
            const int off = (k >> 3) * 512 + pA * 16 + (k & 7) * 2;
            *(uint*)(smem + O_AH + off) = h;
            *(uint*)(smem + O_AL + off) = l;
        }
    };
    if (ag < 4) { doAtom(3 * ag); doAtom(3 * ag + 1); doAtom(3 * ag + 2); }
    else        { int b = 12 + 2 * (ag - 4); doAtom(b); doAtom(b + 1); }
    __syncthreads();   // A image complete — LAST barrier before epilogue

    // ---- B running pointers: wave w owns tiles {4w..4w+3} (+16 for w0) ----
    const ushort* pH  = wsHi + (4 * w * 64 + lane) * 8;
    const ushort* pL  = wsLo + (4 * w * 64 + lane) * 8;
    const ushort* pH2 = wsHi + (16 * 64 + lane) * 8;
    const ushort* pL2 = wsLo + (16 * 64 + lane) * 8;

    f32x4 acc[5][2];
    #pragma unroll
    for (int i = 0; i < 5; ++i)
        #pragma unroll
        for (int mt = 0; mt < 2; ++mt)
            acc[i][mt] = (f32x4){0.0f, 0.0f, 0.0f, 0.0f};

    // ---- barrier-free MFMA k-loop ----
    #pragma unroll 1
    for (int kb = 0; kb < NKB; ++kb) {
        short8 aH[2], aL[2];
        #pragma unroll
        for (int mt = 0; mt < 2; ++mt) {
            const int off = (kb * 4 + lg4) * 512 + (mt * 16 + lr) * 16;
            aH[mt] = *(const short8*)(smem + O_AH + off);
            aL[mt] = *(const short8*)(smem + O_AL + off);
        }
        #pragma unroll
        for (int i = 0; i < 5; ++i) {
            if (i < 4 || w == 0) {
                short8 bh, bl;
                if (USEWS) {
                    if (i < 4) { bh = *(const short8*)(pH + i * 512);
                                 bl = *(const short8*)(pL + i * 512); }
                    else       { bh = *(const short8*)pH2;
                                 bl = *(const short8*)pL2; }
                } else {
                    int nt = (i == 4) ? 16 : (4 * w + i);
                    #pragma unroll
                    for (int j = 0; j < 8; ++j) {
                        int k = kb * 32 + lg4 * 8 + j;
                        int col = nt * 16 + lr;
                        float v = b_src(c2s, norm, k, col);
                        ushort hi = bf16_rne(v);
                        bh[j] = (short)hi;
                        bl[j] = (short)bf16_rne(v - bf16_to_f(hi));
                    }
                }
                #pragma unroll
                for (int mt = 0; mt < 2; ++mt)
                    acc[i][mt] = __builtin_amdgcn_mfma_f32_16x16x32_bf16(aH[mt], bh, acc[i][mt], 0, 0, 0);
                #pragma unroll
                for (int mt = 0; mt < 2; ++mt)
                    acc[i][mt] = __builtin_amdgcn_mfma_f32_16x16x32_bf16(aH[mt], bl, acc[i][mt], 0, 0, 0);
                #pragma unroll
                for (int mt = 0; mt < 2; ++mt)
                    acc[i][mt] = __builtin_amdgcn_mfma_f32_16x16x32_bf16(aL[mt], bh, acc[i][mt], 0, 0, 0);
            }
        }
        pH += BCH; pL += BCH; pH2 += BCH; pL2 += BCH;
    }

    // ---- epilogue: two half-tiles (16 rows) through bounce aliasing A-hi ----
    float* ep = (float*)smem;
    #pragma unroll
    for (int mt = 0; mt < 2; ++mt) {
        __syncthreads();   // all waves past A reads / prior half consumed
        #pragma unroll
        for (int i = 0; i < 5; ++i) {
            if (i < 4 || w == 0) {
                int nt = (i == 4) ? 16 : (4 * w + i);
                int col = nt * 16 + lr;
                #pragma unroll
                for (int r = 0; r < 4; ++r)
                    ep[(lg4 * 4 + r) * EPS + col] = acc[i][mt][r];
            }
        }
        __syncthreads();
        #pragma unroll
        for (int j = 0; j < 4; ++j) {
            int row = w + j * 4;
            int P = P0 + mt * 16 + row;
            if (P < n)
                *(float4*)&out[(size_t)P * NAOS + lane * 4] = *(const float4*)&ep[row * EPS + lane * 4];
        }
        if (w == 1 && lane < 16) {
            int P = P0 + mt * 16 + lane;
            if (P < n)
                *(float4*)&out[(size_t)P * NAOS + 256] = *(const float4*)&ep[lane * EPS + 256];
        }
    }
}

extern "C" void kernel_launch(void* const* d_in, const int* in_sizes, int n_in,
                              void* d_out, int out_size, void* d_ws, size_t ws_size,
                              hipStream_t stream) {
    const float* coords  = (const float*)d_in[0];
    const float* centers = (const float*)d_in[1];
    const float* zetas   = (const float*)d_in[2];
    const float* coeffs  = (const float*)d_in[3];
    const float* norm    = (const float*)d_in[4];
    const float* c2s     = (const float*)d_in[5];
    float* out = (float*)d_out;
    int n = in_sizes[0] / 3;
    int grid = (n + MT - 1) / MT;

    ushort* wsHi = (ushort*)d_ws;
    ushort* wsLo = wsHi + (size_t)KP * NCOLP;
    const size_t WS_NEED = (size_t)2 * KP * NCOLP * sizeof(ushort);

    if (ws_size >= WS_NEED) {
        prep_b<<<(KP * NCOLP + 255) / 256, 256, 0, stream>>>(c2s, norm, wsHi, wsLo);
        gto_mfma<true><<<grid, NTHR, 0, stream>>>(coords, centers, zetas, coeffs, norm, c2s,
                                                  wsHi, wsLo, out, n);
    } else {
        gto_mfma<false><<<grid, NTHR, 0, stream>>>(coords, centers, zetas, coeffs, norm, c2s,
                                                   nullptr, nullptr, out, n);
    }
}

// Round 15
// 89.376 us; speedup vs baseline: 2.7622x; 1.0281x over previous
//
#include <hip/hip_runtime.h>

typedef unsigned int uint;
typedef unsigned short ushort;
typedef __attribute__((ext_vector_type(8))) short short8;   // 8 bf16
typedef __attribute__((ext_vector_type(4))) float f32x4;

#define NSH   100
#define NPRIM 8
#define NAOC  280
#define NAOS  260
#define NATOM 20
#define KP    320           // 20 atoms x 16 k (14 real + 2 zero)
#define NKB   10
#define MT    32            // points per block
#define NTHR  256
#define NCOLP 272
#define BCH   (32 * NCOLP)  // ushorts per chunk image (8704)
#define RSQRT3 0.57735026918962576f
#define LOG2E  1.4426950408889634f
#define EPS   276           // epilogue row stride (floats)

// LDS layout. A image [40 cells][32 p][16B] built ONCE, conflict-free b128.
// Epilogue bounce [0..35328) aliases the (then-dead) A images.
#define O_AH    0        // 40*512 = 20480
#define O_AL    20480    // 20480 -> 40960
#define O_ZETA  40960    // 3200
#define O_COEF  44160    // 3200
#define O_CEN   47360    // 320
#define O_CX    47680    // 128
#define O_CY    47808    // 128
#define O_CZ    47936    // 128 -> 48064
#define POOLSZ  48064    // 3 blocks/CU (LDS); VGPR budget 512/3 ~ 168

__device__ __forceinline__ ushort bf16_rne(float x) {
    uint u = __float_as_uint(x);
    return (ushort)((u + 0x7FFFu + ((u >> 16) & 1u)) >> 16);
}
__device__ __forceinline__ float bf16_to_f(ushort h) {
    return __uint_as_float(((uint)h) << 16);
}
__device__ __forceinline__ uint cvt_pk_bf16(float a, float b) {
    uint r;
    asm("v_cvt_pk_bf16_f32 %0, %1, %2" : "=v"(r) : "v"(a), "v"(b));
    return r;
}

// B source in atom-major 16-padded k ordering: k' = 16a + i,
// i: 0,1 = s; 2..4 = p0 xyz; 5..7 = p1 xyz; 8..13 = d (xx,xy,xz,yy,yz,zz); 14,15 = 0.
// normalization and the d anorm (1/sqrt(3) on xx,yy,zz) folded in.
__device__ __forceinline__ float b_src(const float* __restrict__ c2s,
                                       const float* __restrict__ norm,
                                       int kp, int col) {
    if (kp >= KP || col >= NAOS) return 0.0f;
    int a = kp >> 4, i = kp & 15;
    if (i >= 14) return 0.0f;
    int ksrc; float an = 1.0f;
    if (i < 2)      ksrc = 2 * a + i;
    else if (i < 8) ksrc = 40 + 6 * a + (i - 2);
    else {
        ksrc = 160 + 6 * a + (i - 8);
        if (i == 8 || i == 11 || i == 13) an = RSQRT3;
    }
    return c2s[ksrc * NAOS + col] * norm[ksrc] * an;
}

// ---- prep: permuted+scaled cart2sph -> bf16 hi/lo MFMA frag image ----
__global__ void prep_b(const float* __restrict__ c2s, const float* __restrict__ norm,
                       ushort* __restrict__ wsHi, ushort* __restrict__ wsLo) {
    int id = blockIdx.x * 256 + threadIdx.x;
    if (id >= KP * NCOLP) return;
    int k = id / NCOLP, col = id % NCOLP;
    float v = b_src(c2s, norm, k, col);
    ushort hi = bf16_rne(v);
    ushort lo = bf16_rne(v - bf16_to_f(hi));
    int off = (k >> 5) * BCH +
              (((col >> 4) * 4 + ((k & 31) >> 3)) * 16 + (col & 15)) * 8 + (k & 7);
    wsHi[off] = hi;
    wsLo[off] = lo;
}

template <bool USEWS>
__global__ __launch_bounds__(NTHR, 3) void gto_mfma(
    const float* __restrict__ coords, const float* __restrict__ centers,
    const float* __restrict__ zetas, const float* __restrict__ coeffs,
    const float* __restrict__ norm, const float* __restrict__ c2s,
    const ushort* __restrict__ wsHi, const ushort* __restrict__ wsLo,
    float* __restrict__ out, int n)
{
    __shared__ __align__(16) char smem[POOLSZ];
    float*  sZeta = (float*)(smem + O_ZETA);
    float*  sCoef = (float*)(smem + O_COEF);
    float4* sCen4 = (float4*)(smem + O_CEN);
    float*  sCx   = (float*)(smem + O_CX);
    float*  sCy   = (float*)(smem + O_CY);
    float*  sCz   = (float*)(smem + O_CZ);

    const int t = threadIdx.x, lane = t & 63, w = t >> 6;
    const int lr = lane & 15, lg4 = lane >> 4;
    const int P0 = blockIdx.x * MT;

    // ---- stage constants ----
    for (int i = t; i < NSH * NPRIM; i += NTHR) {
        sZeta[i] = zetas[i] * LOG2E;           // pre-fold log2e for v_exp_f32
        sCoef[i] = coeffs[i];
    }
    if (t < NATOM)
        sCen4[t] = make_float4(centers[3 * t], centers[3 * t + 1], centers[3 * t + 2], 0.0f);
    if (t < MT * 3) {
        int gi = P0 * 3 + t;
        float v = (gi < 3 * n) ? coords[gi] : 0.0f;
        int p = t / 3, c = t - 3 * (t / 3);
        if (c == 0) sCx[p] = v; else if (c == 1) sCy[p] = v; else sCz[p] = v;
    }
    __syncthreads();

    // ---- A-build: FULLY STATIC per (point, atom); 16-k cells, b128 writes ----
    const int pA = t & 31, ag = t >> 5;
    const float cxp = sCx[pA], cyp = sCy[pA], czp = sCz[pA];

    auto doAtom = [&](int a) {
        float4 ca = sCen4[a];
        float dx = cxp - ca.x, dy = cyp - ca.y, dz = czp - ca.z;
        float r2 = dx * dx + dy * dy + dz * dz;
        float rad[5];
        #pragma unroll
        for (int sh = 0; sh < 5; ++sh) {
            const float* z = &sZeta[(5 * a + sh) * NPRIM];
            const float* cf = &sCoef[(5 * a + sh) * NPRIM];
            float4 z0 = *(const float4*)z,  z1 = *(const float4*)(z + 4);
            float4 c0 = *(const float4*)cf, c1 = *(const float4*)(cf + 4);
            float r = c0.x * __builtin_amdgcn_exp2f(-z0.x * r2);
            r += c0.y * __builtin_amdgcn_exp2f(-z0.y * r2);
            r += c0.z * __builtin_amdgcn_exp2f(-z0.z * r2);
            r += c0.w * __builtin_amdgcn_exp2f(-z0.w * r2);
            r += c1.x * __builtin_amdgcn_exp2f(-z1.x * r2);
            r += c1.y * __builtin_amdgcn_exp2f(-z1.y * r2);
            r += c1.z * __builtin_amdgcn_exp2f(-z1.z * r2);
            r += c1.w * __builtin_amdgcn_exp2f(-z1.w * r2);
            rad[sh] = r;
        }
        float xx = dx * dx, xy = dx * dy, xz = dx * dz;
        float yy = dy * dy, yz = dy * dz, zz = dz * dz;
        float v[14] = { rad[0], rad[1],
                        dx * rad[2], dy * rad[2], dz * rad[2],
                        dx * rad[3], dy * rad[3], dz * rad[3],
                        xx * rad[4], xy * rad[4], xz * rad[4],
                        yy * rad[4], yz * rad[4], zz * rad[4] };
        uint h[7], l[7];
        #pragma unroll
        for (int pr = 0; pr < 7; ++pr) {
            h[pr] = cvt_pk_bf16(v[2 * pr], v[2 * pr + 1]);
            float r0 = v[2 * pr]     - __uint_as_float(h[pr] << 16);
            float r1 = v[2 * pr + 1] - __uint_as_float(h[pr] & 0xffff0000u);
            l[pr] = cvt_pk_bf16(r0, r1);
        }
        const int off = a * 1024 + pA * 16;   // cells 2a, 2a+1; 16B aligned
        *(uint4*)(smem + O_AH + off)       = make_uint4(h[0], h[1], h[2], h[3]);
        *(uint4*)(smem + O_AH + off + 512) = make_uint4(h[4], h[5], h[6], 0u);
        *(uint4*)(smem + O_AL + off)       = make_uint4(l[0], l[1], l[2], l[3]);
        *(uint4*)(smem + O_AL + off + 512) = make_uint4(l[4], l[5], l[6], 0u);
    };
    if (ag < 4) { doAtom(3 * ag); doAtom(3 * ag + 1); doAtom(3 * ag + 2); }
    else        { int b = 12 + 2 * (ag - 4); doAtom(b); doAtom(b + 1); }
    __syncthreads();   // A image complete — barrier-free k-loop follows

    // ---- B running pointers: wave w owns tiles {4w..4w+3} (+16 for w0) ----
    const ushort* pH  = wsHi + (4 * w * 64 + lane) * 8;
    const ushort* pL  = wsLo + (4 * w * 64 + lane) * 8;
    const ushort* pH2 = wsHi + (16 * 64 + lane) * 8;
    const ushort* pL2 = wsLo + (16 * 64 + lane) * 8;

    f32x4 acc[5][2];
    #pragma unroll
    for (int i = 0; i < 5; ++i)
        #pragma unroll
        for (int mt = 0; mt < 2; ++mt)
            acc[i][mt] = (f32x4){0.0f, 0.0f, 0.0f, 0.0f};

    // ---- barrier-free MFMA k-loop; B tiles batch-loaded per chunk ----
    #pragma unroll 1
    for (int kb = 0; kb < NKB; ++kb) {
        // batched B loads (MLP: all issued back-to-back, one L2 latency/chunk)
        short8 bh[5], bl[5];
        if (USEWS) {
            #pragma unroll
            for (int i = 0; i < 4; ++i) {
                bh[i] = *(const short8*)(pH + i * 512);
                bl[i] = *(const short8*)(pL + i * 512);
            }
            if (w == 0) {
                bh[4] = *(const short8*)pH2;
                bl[4] = *(const short8*)pL2;
            }
        } else {
            #pragma unroll
            for (int i = 0; i < 5; ++i) {
                int nt = (i == 4) ? 16 : (4 * w + i);
                #pragma unroll
                for (int j = 0; j < 8; ++j) {
                    int k = kb * 32 + lg4 * 8 + j;
                    int col = nt * 16 + lr;
                    float v = b_src(c2s, norm, k, col);
                    ushort hi = bf16_rne(v);
                    bh[i][j] = (short)hi;
                    bl[i][j] = (short)bf16_rne(v - bf16_to_f(hi));
                }
            }
        }

        short8 aH[2], aL[2];
        #pragma unroll
        for (int mt = 0; mt < 2; ++mt) {
            const int off = (kb * 4 + lg4) * 512 + (mt * 16 + lr) * 16;
            aH[mt] = *(const short8*)(smem + O_AH + off);
            aL[mt] = *(const short8*)(smem + O_AL + off);
        }

        #pragma unroll
        for (int i = 0; i < 5; ++i) {
            if (i < 4 || w == 0) {
                #pragma unroll
                for (int mt = 0; mt < 2; ++mt)
                    acc[i][mt] = __builtin_amdgcn_mfma_f32_16x16x32_bf16(aH[mt], bh[i], acc[i][mt], 0, 0, 0);
                #pragma unroll
                for (int mt = 0; mt < 2; ++mt)
                    acc[i][mt] = __builtin_amdgcn_mfma_f32_16x16x32_bf16(aH[mt], bl[i], acc[i][mt], 0, 0, 0);
                #pragma unroll
                for (int mt = 0; mt < 2; ++mt)
                    acc[i][mt] = __builtin_amdgcn_mfma_f32_16x16x32_bf16(aL[mt], bh[i], acc[i][mt], 0, 0, 0);
            }
        }
        pH += BCH; pL += BCH; pH2 += BCH; pL2 += BCH;
    }

    // ---- epilogue: single 32-row bounce (aliases dead A images) ----
    __syncthreads();   // all waves done reading A image
    float* ep = (float*)smem;
    #pragma unroll
    for (int i = 0; i < 5; ++i) {
        if (i < 4 || w == 0) {
            int nt = (i == 4) ? 16 : (4 * w + i);
            int col = nt * 16 + lr;
            #pragma unroll
            for (int mt = 0; mt < 2; ++mt)
                #pragma unroll
                for (int r = 0; r < 4; ++r)
                    ep[(mt * 16 + lg4 * 4 + r) * EPS + col] = acc[i][mt][r];
        }
    }
    __syncthreads();

    #pragma unroll
    for (int j = 0; j < 8; ++j) {
        int row = w + j * 4;
        int P = P0 + row;
        if (P < n)
            *(float4*)&out[(size_t)P * NAOS + lane * 4] = *(const float4*)&ep[row * EPS + lane * 4];
    }
    if (w == 1 && lane < MT) {
        int P = P0 + lane;
        if (P < n)
            *(float4*)&out[(size_t)P * NAOS + 256] = *(const float4*)&ep[lane * EPS + 256];
    }
}

extern "C" void kernel_launch(void* const* d_in, const int* in_sizes, int n_in,
                              void* d_out, int out_size, void* d_ws, size_t ws_size,
                              hipStream_t stream) {
    const float* coords  = (const float*)d_in[0];
    const float* centers = (const float*)d_in[1];
    const float* zetas   = (const float*)d_in[2];
    const float* coeffs  = (const float*)d_in[3];
    const float* norm    = (const float*)d_in[4];
    const float* c2s     = (const float*)d_in[5];
    float* out = (float*)d_out;
    int n = in_sizes[0] / 3;
    int grid = (n + MT - 1) / MT;

    ushort* wsHi = (ushort*)d_ws;
    ushort* wsLo = wsHi + (size_t)KP * NCOLP;
    const size_t WS_NEED = (size_t)2 * KP * NCOLP * sizeof(ushort);   // 348160

    if (ws_size >= WS_NEED) {
        prep_b<<<(KP * NCOLP + 255) / 256, 256, 0, stream>>>(c2s, norm, wsHi, wsLo);
        gto_mfma<true><<<grid, NTHR, 0, stream>>>(coords, centers, zetas, coeffs, norm, c2s,
                                                  wsHi, wsLo, out, n);
    } else {
        gto_mfma<false><<<grid, NTHR, 0, stream>>>(coords, centers, zetas, coeffs, norm, c2s,
                                                   nullptr, nullptr, out, n);
    }
}